// Round 1
// baseline (289.042 us; speedup 1.0000x reference)
//
#include <hip/hip_runtime.h>

#define D_ 300
#define C_ 10
#define I_ 6
#define NPOS 16384
#define PPB 4                 // positions (one wave each) per block
#define NBLK (NPOS / PPB)     // 4096 blocks
#define NDOT 70               // 10 contexts x (1 target-score + 6 info-scores)
#define NGRP 16               // lane groups of 4 after DPP quad pre-reduce

__device__ __forceinline__ float neg_log_sigmoid(float x) {
    // -log_sigmoid(x) = log(1 + exp(-x)); x in [-10,10] so fp32 is safe
    return __logf(1.0f + __expf(-x));
}

// One wave per position. Lane l holds feature k = 4*l..4*l+3 (float4) plus
// tail k = 256+l for l < 44. Dots are pre-reduced 4:1 in-register via DPP
// quad shuffles, then staged to a small LDS buffer ([70][17] per wave =
// 19,056 B/block -> 8 blocks/CU; old [35][65]x2-chunk layout was 36,864 B
// -> 4 blocks/CU, the occupancy limiter).
__global__ __launch_bounds__(256, 8) void hg2vec_pos_kernel(
    const int* __restrict__ pos_u, const int* __restrict__ pos_v,
    const int* __restrict__ info_v,
    const float* __restrict__ W_in, const float* __restrict__ W_out,
    const float* __restrict__ context_mask, const float* __restrict__ sig_mask,
    const float* __restrict__ score_mask, float* __restrict__ partial)
{
    const int wave = threadIdx.x >> 6;
    const int lane = threadIdx.x & 63;
    const int p = blockIdx.x * PPB + wave;
    // Uniform position id -> index loads become scalar (SMEM) loads.
    const int sp = __builtin_amdgcn_readfirstlane(p);

    __shared__ float s_red[PPB][NDOT][NGRP + 1];  // +1 pad: conflict-free read
    __shared__ float s_wsum[PPB];

    const int su = pos_u[sp];
    int scv[C_], siv[I_];
#pragma unroll
    for (int c = 0; c < C_; ++c) scv[c] = pos_v[sp * C_ + c];
#pragma unroll
    for (int i = 0; i < I_; ++i) siv[i] = info_v[sp * I_ + i];

    // Tail: k4 = 256+lane valid only for lane < 44; clamp address, zero value.
    const int k4 = lane + 256;
    const float okf = (k4 < D_) ? 1.0f : 0.0f;
    const int k4c = (k4 < D_) ? k4 : lane;

    // Target row u = W_out[su]: float4 + zeroed tail scalar (5 VGPRs)
    const float* ur = W_out + (size_t)su * D_;
    float4 uv = *(const float4*)(ur + 4 * lane);
    float u4 = ur[k4c] * okf;

    // Info rows W_in[siv[i]], resident (6 x 5 VGPRs), tails zeroed
    float4 iv[I_];
    float it[I_];
#pragma unroll
    for (int i = 0; i < I_; ++i) {
        const float* r = W_in + (size_t)siv[i] * D_;
        iv[i] = *(const float4*)(r + 4 * lane);
        it[i] = r[k4c] * okf;
    }

#pragma unroll
    for (int c = 0; c < C_; ++c) {
        const float* cir = W_in  + (size_t)scv[c] * D_;
        const float* cor = W_out + (size_t)scv[c] * D_;
        float4 av = *(const float4*)(cir + 4 * lane);
        float  a4 = cir[k4c];                 // tail garbage * u4==0 -> ok
        float4 bv = *(const float4*)(cor + 4 * lane);
        float  b4 = cor[k4c];                 // tail garbage * it==0 -> ok

        float pr[7];
        pr[0] = uv.x * av.x + uv.y * av.y + uv.z * av.z + uv.w * av.w + u4 * a4;
#pragma unroll
        for (int i = 0; i < I_; ++i)
            pr[1 + i] = bv.x * iv[i].x + bv.y * iv[i].y +
                        bv.z * iv[i].z + bv.w * iv[i].w + b4 * it[i];

        // 4:1 quad pre-reduce (DPP), one ds_write per dot from quad leaders.
#pragma unroll
        for (int t = 0; t < 7; ++t) {
            float v = pr[t];
            v += __shfl_xor(v, 1, 64);
            v += __shfl_xor(v, 2, 64);
            if ((lane & 3) == 0) s_red[wave][c * 7 + t][lane >> 2] = v;
        }
    }

    __syncthreads();   // single barrier per position (was 4)

    float acc = 0.0f;
    if (lane < 35) {
#pragma unroll
        for (int rep = 0; rep < 2; ++rep) {
            const int d = lane + rep * 35;            // 0..69
            const float* rowp = s_red[wave][d];
            float s0 = rowp[0] + rowp[4] + rowp[8]  + rowp[12];
            float s1 = rowp[1] + rowp[5] + rowp[9]  + rowp[13];
            float s2 = rowp[2] + rowp[6] + rowp[10] + rowp[14];
            float s3 = rowp[3] + rowp[7] + rowp[11] + rowp[15];
            float dot = (s0 + s1) + (s2 + s3);
            const int c = d / 7;
            const int t = d - c * 7;
            float term;
            if (t == 0) {
                // score = dot(u, mask*cin) = mask*dot; clip; -logsig
                float x = dot * context_mask[c];
                x = fminf(fmaxf(x, -10.0f), 10.0f);
                term = neg_log_sigmoid(x);
            } else {
                const int i = t - 1;
                float x = fminf(fmaxf(dot, -10.0f), 10.0f) * sig_mask[i];
                term = neg_log_sigmoid(x) * score_mask[i];
            }
            acc += term;
        }
    }

    // per-wave total (lanes >= 35 contribute 0)
#pragma unroll
    for (int off = 32; off; off >>= 1) acc += __shfl_xor(acc, off, 64);
    if (lane == 0) s_wsum[wave] = acc;
    __syncthreads();
    if (threadIdx.x == 0)
        partial[blockIdx.x] = s_wsum[0] + s_wsum[1] + s_wsum[2] + s_wsum[3];
}

// Single block, 1024 threads: 4096 partials = 1024 float4, one per thread.
__global__ __launch_bounds__(1024) void hg2vec_reduce_kernel(
    const float* __restrict__ partial, float* __restrict__ out)
{
    float4 v = ((const float4*)partial)[threadIdx.x];
    float a = (v.x + v.y) + (v.z + v.w);
#pragma unroll
    for (int off = 32; off; off >>= 1) a += __shfl_xor(a, off, 64);
    __shared__ float s[16];
    if ((threadIdx.x & 63) == 0) s[threadIdx.x >> 6] = a;
    __syncthreads();
    if (threadIdx.x == 0) {
        float t = 0;
#pragma unroll
        for (int i = 0; i < 16; ++i) t += s[i];
        out[0] = t;
    }
}

extern "C" void kernel_launch(void* const* d_in, const int* in_sizes, int n_in,
                              void* d_out, int out_size, void* d_ws, size_t ws_size,
                              hipStream_t stream) {
    const int* pos_u = (const int*)d_in[0];
    const int* pos_v = (const int*)d_in[1];
    const int* info_v = (const int*)d_in[2];
    const float* W_in = (const float*)d_in[3];
    const float* W_out = (const float*)d_in[4];
    const float* context_mask = (const float*)d_in[5];
    const float* sig_mask = (const float*)d_in[6];
    const float* score_mask = (const float*)d_in[7];
    float* out = (float*)d_out;
    float* partial = (float*)d_ws;   // NBLK floats = 16 KB scratch

    hg2vec_pos_kernel<<<NBLK, 256, 0, stream>>>(
        pos_u, pos_v, info_v, W_in, W_out,
        context_mask, sig_mask, score_mask, partial);
    hg2vec_reduce_kernel<<<1, 1024, 0, stream>>>(partial, out);
}

// Round 2
// 288.915 us; speedup vs baseline: 1.0004x; 1.0004x over previous
//
#include <hip/hip_runtime.h>

#define D_ 300
#define C_ 10
#define I_ 6
#define NPOS 16384
#define PPB 4                 // positions (one wave each) per block
#define NBLK (NPOS / PPB)     // 4096 blocks
#define NDOT 70               // 10 contexts x (1 target-score + 6 info-scores)
#define NGRP 16               // lane groups of 4 after DPP quad pre-reduce

__device__ __forceinline__ float neg_log_sigmoid(float x) {
    // -log_sigmoid(x) = log(1 + exp(-x)); x in [-10,10] so fp32 is safe
    return __logf(1.0f + __expf(-x));
}

// One wave per position. Lane l holds feature k = 4*l..4*l+3 (float4) plus
// tail k = 256+l for l < 44.
//
// launch_bounds(256,6) -> 80-VGPR cap. NOT 8: at the 64-reg cap the
// allocator refuses to keep the 35 resident regs (uv,u4,iv[6],it[6]) and
// reloads info rows inside the c-loop (round-1: VGPR_Count=28, flat perf).
// 80 regs fit residents + a 2-deep prefetch pipeline.
__global__ __launch_bounds__(256, 6) void hg2vec_pos_kernel(
    const int* __restrict__ pos_u, const int* __restrict__ pos_v,
    const int* __restrict__ info_v,
    const float* __restrict__ W_in, const float* __restrict__ W_out,
    const float* __restrict__ context_mask, const float* __restrict__ sig_mask,
    const float* __restrict__ score_mask, float* __restrict__ partial)
{
    const int wave = threadIdx.x >> 6;
    const int lane = threadIdx.x & 63;
    const int p = blockIdx.x * PPB + wave;
    // Uniform position id -> index loads become scalar (SMEM) loads.
    const int sp = __builtin_amdgcn_readfirstlane(p);

    __shared__ float s_red[PPB][NDOT][NGRP + 1];  // 19,056 B/block
    __shared__ float s_wsum[PPB];

    const int su = pos_u[sp];
    int scv[C_], siv[I_];
#pragma unroll
    for (int c = 0; c < C_; ++c) scv[c] = pos_v[sp * C_ + c];
#pragma unroll
    for (int i = 0; i < I_; ++i) siv[i] = info_v[sp * I_ + i];

    // Tail: k4 = 256+lane valid only for lane < 44; clamp address, zero value.
    const int k4 = lane + 256;
    const float okf = (k4 < D_) ? 1.0f : 0.0f;
    const int k4c = (k4 < D_) ? k4 : lane;

    // Target row u = W_out[su]: float4 + zeroed tail scalar (5 VGPRs)
    const float* ur = W_out + (size_t)su * D_;
    float4 uv = *(const float4*)(ur + 4 * lane);
    float u4 = ur[k4c] * okf;

    // Info rows W_in[siv[i]], resident (6 x 5 VGPRs), tails zeroed
    float4 iv[I_];
    float it[I_];
#pragma unroll
    for (int i = 0; i < I_; ++i) {
        const float* r = W_in + (size_t)siv[i] * D_;
        iv[i] = *(const float4*)(r + 4 * lane);
        it[i] = r[k4c] * okf;
    }

    // ---- 2-deep software pipeline over contexts ----
    // Prefetch context 0
    {
        const float* cir = W_in  + (size_t)scv[0] * D_;
        const float* cor = W_out + (size_t)scv[0] * D_;
        float4 av = *(const float4*)(cir + 4 * lane);
        float  a4 = cir[k4c];                 // tail garbage * u4==0 -> ok
        float4 bv = *(const float4*)(cor + 4 * lane);
        float  b4 = cor[k4c];                 // tail garbage * it==0 -> ok

#pragma unroll
        for (int c = 0; c < C_; ++c) {
            float4 avn, bvn;
            float  a4n = 0.0f, b4n = 0.0f;
            if (c + 1 < C_) {                 // issue next context's gathers NOW
                const float* cirn = W_in  + (size_t)scv[c + 1] * D_;
                const float* corn = W_out + (size_t)scv[c + 1] * D_;
                avn = *(const float4*)(cirn + 4 * lane);
                a4n = cirn[k4c];
                bvn = *(const float4*)(corn + 4 * lane);
                b4n = corn[k4c];
            }

            // dot t=0: u . ctx_in  — compute, quad-reduce, stage immediately
            {
                float v = uv.x * av.x + uv.y * av.y + uv.z * av.z +
                          uv.w * av.w + u4 * a4;
                v += __shfl_xor(v, 1, 64);
                v += __shfl_xor(v, 2, 64);
                if ((lane & 3) == 0) s_red[wave][c * 7][lane >> 2] = v;
            }
            // dots t=1..6: ctx_out . info_in[i]
#pragma unroll
            for (int i = 0; i < I_; ++i) {
                float v = bv.x * iv[i].x + bv.y * iv[i].y +
                          bv.z * iv[i].z + bv.w * iv[i].w + b4 * it[i];
                v += __shfl_xor(v, 1, 64);
                v += __shfl_xor(v, 2, 64);
                if ((lane & 3) == 0) s_red[wave][c * 7 + 1 + i][lane >> 2] = v;
            }

            av = avn; a4 = a4n; bv = bvn; b4 = b4n;  // rotate pipeline
        }
    }

    __syncthreads();   // single barrier per position

    float acc = 0.0f;
    if (lane < 35) {
#pragma unroll
        for (int rep = 0; rep < 2; ++rep) {
            const int d = lane + rep * 35;            // 0..69
            const float* rowp = s_red[wave][d];
            float s0 = rowp[0] + rowp[4] + rowp[8]  + rowp[12];
            float s1 = rowp[1] + rowp[5] + rowp[9]  + rowp[13];
            float s2 = rowp[2] + rowp[6] + rowp[10] + rowp[14];
            float s3 = rowp[3] + rowp[7] + rowp[11] + rowp[15];
            float dot = (s0 + s1) + (s2 + s3);
            const int c = d / 7;
            const int t = d - c * 7;
            float term;
            if (t == 0) {
                // score = dot(u, mask*cin) = mask*dot; clip; -logsig
                float x = dot * context_mask[c];
                x = fminf(fmaxf(x, -10.0f), 10.0f);
                term = neg_log_sigmoid(x);
            } else {
                const int i = t - 1;
                float x = fminf(fmaxf(dot, -10.0f), 10.0f) * sig_mask[i];
                term = neg_log_sigmoid(x) * score_mask[i];
            }
            acc += term;
        }
    }

    // per-wave total (lanes >= 35 contribute 0)
#pragma unroll
    for (int off = 32; off; off >>= 1) acc += __shfl_xor(acc, off, 64);
    if (lane == 0) s_wsum[wave] = acc;
    __syncthreads();
    if (threadIdx.x == 0)
        partial[blockIdx.x] = s_wsum[0] + s_wsum[1] + s_wsum[2] + s_wsum[3];
}

// Single block, 1024 threads: 4096 partials = 1024 float4, one per thread.
__global__ __launch_bounds__(1024) void hg2vec_reduce_kernel(
    const float* __restrict__ partial, float* __restrict__ out)
{
    float4 v = ((const float4*)partial)[threadIdx.x];
    float a = (v.x + v.y) + (v.z + v.w);
#pragma unroll
    for (int off = 32; off; off >>= 1) a += __shfl_xor(a, off, 64);
    __shared__ float s[16];
    if ((threadIdx.x & 63) == 0) s[threadIdx.x >> 6] = a;
    __syncthreads();
    if (threadIdx.x == 0) {
        float t = 0;
#pragma unroll
        for (int i = 0; i < 16; ++i) t += s[i];
        out[0] = t;
    }
}

extern "C" void kernel_launch(void* const* d_in, const int* in_sizes, int n_in,
                              void* d_out, int out_size, void* d_ws, size_t ws_size,
                              hipStream_t stream) {
    const int* pos_u = (const int*)d_in[0];
    const int* pos_v = (const int*)d_in[1];
    const int* info_v = (const int*)d_in[2];
    const float* W_in = (const float*)d_in[3];
    const float* W_out = (const float*)d_in[4];
    const float* context_mask = (const float*)d_in[5];
    const float* sig_mask = (const float*)d_in[6];
    const float* score_mask = (const float*)d_in[7];
    float* out = (float*)d_out;
    float* partial = (float*)d_ws;   // NBLK floats = 16 KB scratch

    hg2vec_pos_kernel<<<NBLK, 256, 0, stream>>>(
        pos_u, pos_v, info_v, W_in, W_out,
        context_mask, sig_mask, score_mask, partial);
    hg2vec_reduce_kernel<<<1, 1024, 0, stream>>>(partial, out);
}